// Round 11
// baseline (333.898 us; speedup 1.0000x reference)
//
#include <hip/hip_runtime.h>
#include <hip/hip_bf16.h>
#include <stdint.h>

#define DD 128
#define CHUNK 1024

typedef short bf16x8 __attribute__((ext_vector_type(8)));
typedef short bf16x4 __attribute__((ext_vector_type(4)));
typedef float f32x4 __attribute__((ext_vector_type(4)));
typedef uint32_t u32x4 __attribute__((ext_vector_type(4)));

// LDS-only barrier: drain this wave's LDS ops, sync — global loads stay in flight.
#define LGKM_BAR() do{ asm volatile("s_waitcnt lgkmcnt(0)" ::: "memory"); \
                       __builtin_amdgcn_s_barrier(); }while(0)

__device__ __forceinline__ short f2bf(float f){
  union { float f; uint32_t u; } v; v.f = f;
  uint32_t r = v.u + 0x7fffu + ((v.u >> 16) & 1u);
  return (short)(r >> 16);
}
__device__ __forceinline__ float bf2f(short s){
  union { uint32_t u; float f; } v; v.u = ((uint32_t)(uint16_t)s) << 16;
  return v.f;
}
__device__ __forceinline__ uint32_t cvt_pk_bf16(float a, float b){
  uint32_t r;
  asm("v_cvt_pk_bf16_f32 %0, %1, %2" : "=v"(r) : "v"(a), "v"(b));
  return r;
}
__device__ __forceinline__ float sigm(float x){ return 1.0f/(1.0f + __expf(-x)); }
__device__ __forceinline__ float tanh_f(float x){ return 1.0f - 2.0f/(__expf(2.0f*x) + 1.0f); }

// ---------------- init: deg=1, edge-dtype detect, all weight transposes ----------------

__global__ __launch_bounds__(256) void init_k(int* deg, const int* e32, int* flag,
    const float* Wg, const float* Wz, const float* Wr, const float* Wh,
    short* wtg, short* wtzr, short* wth, int n, int e){
  int i = blockIdx.x*256 + threadIdx.x;
  if(i < n) deg[i] = 1;                       // self loop
  if(i < e && e32[2*i+1] != 0) *flag = 1;     // int32 storage detected (benign race)
  if(i < 16384){
    int nn = i >> 7, k = i & 127;
    wtg[i] = f2bf(Wg[k*128 + nn]);
  } else if(i < 49152){
    int j = i - 16384; int c = j >> 8, k = j & 255;       // c = Z logical col
    int p = (c >> 5)*64 + (((c >> 4) & 1)*16) + (c & 15); // phys col
    wtzr[p*256 + k] = f2bf(Wz[k*128 + c]);
  } else if(i < 81920){
    int j = i - 49152; int c = j >> 8, k = j & 255;       // c = R logical col
    int p = (c >> 5)*64 + 32 + (((c >> 4) & 1)*16) + (c & 15);
    wtzr[p*256 + k] = f2bf(Wr[k*128 + c]);
  } else if(i < 114688){
    int j = i - 81920; int nn = j >> 8, k = j & 255;
    wth[nn*256 + k] = f2bf(Wh[k*128 + nn]);
  }
}

__device__ __forceinline__ int eidx(const int* e32, int is32, long pos, int n){
  int v = is32 ? e32[pos] : e32[2*pos];
  return v < 0 ? 0 : (v >= n ? n-1 : v);
}

__global__ void deg_k(const int* e32, const int* flag, int* deg, int e, int n){
  int i = blockIdx.x*256 + threadIdx.x;
  if(i >= e) return;
  int is32 = *flag;
  int c = eidx(e32, is32, (long)e + i, n);  // cols = targets
  atomicAdd(&deg[c], 1);
}

// ---------------- scanA (per-chunk sums) + dinv, merged ----------------

__global__ __launch_bounds__(256) void dscanA_k(const int* deg, int* bsum,
                                                float* dinv, int n, int nb){
  int t = threadIdx.x;
  if((int)blockIdx.x < nb){
    __shared__ int ls[256];
    int b = blockIdx.x;
    int base = b*CHUNK + t*4;
    int s = 0;
    #pragma unroll
    for(int j = 0; j < 4; j++){ int i = base + j; if(i < n) s += deg[i] - 1; }
    ls[t] = s; __syncthreads();
    for(int off = 128; off > 0; off >>= 1){
      if(t < off) ls[t] += ls[t+off];
      __syncthreads();
    }
    if(t == 0) bsum[b] = ls[0];
  } else {
    int i = (blockIdx.x - nb)*256 + t;
    if(i < n) dinv[i] = rsqrtf((float)deg[i]);
  }
}

// ---------------- scanB (parallel exclusive scan of bsum) + cvtxh, merged ----------

__global__ __launch_bounds__(256) void scanBcvt_k(int* bsum, int nb,
    const float* x, const float* H, const float* dinv, short* xs, short* Hb, int n){
  int t = threadIdx.x;
  if(blockIdx.x == 0){
    if(nb <= 256){
      __shared__ int ls[256];
      int v = (t < nb) ? bsum[t] : 0;
      ls[t] = v; __syncthreads();
      for(int d = 1; d < 256; d <<= 1){
        int tmp = (t >= d) ? ls[t-d] : 0;
        __syncthreads();
        ls[t] += tmp;
        __syncthreads();
      }
      if(t < nb) bsum[t] = ls[t] - v;   // exclusive
    } else if(t == 0){
      int acc = 0;
      for(int i = 0; i < nb; i++){ int v = bsum[i]; bsum[i] = acc; acc += v; }
    }
  } else {
    long i = (long)(blockIdx.x - 1)*256 + t;
    long tot = (long)n*(DD/8);
    if(i >= 2*tot) return;
    bool isH = i >= tot;
    long j = isH ? i - tot : i;
    const float* src = isH ? H : x;
    f32x4 a = *(const f32x4*)(src + j*8);
    f32x4 b = *(const f32x4*)(src + j*8 + 4);
    float sc = isH ? 1.f : dinv[(int)(j >> 4)];
    u32x4 o;
    o[0] = cvt_pk_bf16(a[0]*sc, a[1]*sc);
    o[1] = cvt_pk_bf16(a[2]*sc, a[3]*sc);
    o[2] = cvt_pk_bf16(b[0]*sc, b[1]*sc);
    o[3] = cvt_pk_bf16(b[2]*sc, b[3]*sc);
    *(u32x4*)((isH ? Hb : xs) + j*8) = o;
  }
}

__global__ __launch_bounds__(256) void scanC_k(const int* deg, const int* bsum,
                                               int* off, int* cursor, int n){
  __shared__ int ls[256];
  int b = blockIdx.x, t = threadIdx.x;
  int base = b*CHUNK + t*4;
  int v[4]; int s = 0;
  #pragma unroll
  for(int j = 0; j < 4; j++){ int i = base + j; v[j] = (i < n) ? deg[i]-1 : 0; s += v[j]; }
  ls[t] = s; __syncthreads();
  for(int d = 1; d < 256; d <<= 1){
    int tmp = (t >= d) ? ls[t-d] : 0;
    __syncthreads();
    ls[t] += tmp;
    __syncthreads();
  }
  int run = bsum[b] + ls[t] - s;   // exclusive prefix
  #pragma unroll
  for(int j = 0; j < 4; j++){
    int i = base + j;
    if(i < n){ off[i] = run; cursor[i] = run; run += v[j]; }
  }
}

__global__ void fill_k(const int* e32, const int* flag, int* cursor, int* srcs,
                       int e, int n){
  int i = blockIdx.x*256 + threadIdx.x;
  if(i >= e) return;
  int is32 = *flag;
  int r = eidx(e32, is32, i, n);
  int c = eidx(e32, is32, (long)e + i, n);
  int slot = atomicAdd(&cursor[c], 1);
  srcs[slot] = r;
}

// ---------------- fused GCN: CSR gather (bf16, pre-scaled) -> LDS -> GEMM ----------

__global__ __launch_bounds__(256) void gcn_k(const short* xs, const float* dinv,
    const int* offs, const int* deg, const int* srcs, const short* wt,
    const float* bias, short* hraw, float* sum, float* sumsq, int n){
  __shared__ char Alds[64*256];  // 64 rows x 128 bf16, XOR-swizzled
  const int t = threadIdx.x;
  const int row0 = blockIdx.x*64;
  const int w = t >> 6, ll = t & 63;
  const int lrow = ll & 15, lk = ll >> 4;
  // ---- preload all B fragments (independent of everything) ----
  bf16x8 Bg[2][4];
  #pragma unroll
  for(int j = 0; j < 2; j++){
    int col = (w*2+j)*16 + lrow;
    #pragma unroll
    for(int ks = 0; ks < 4; ks++)
      Bg[j][ks] = *(const bf16x8*)(wt + col*128 + ks*32 + lk*8);
  }
  // ---- gather ----
  const int g = t >> 4, lane16 = t & 15;
  for(int rr = 0; rr < 4; rr++){
    int row = g*4 + rr;
    int node = row0 + row;
    float acc[8] = {0,0,0,0,0,0,0,0};
    if(node < n){
      float di = dinv[node];
      bf16x8 sv = *(const bf16x8*)(xs + (long)node*DD + lane16*8);
      #pragma unroll
      for(int c = 0; c < 8; c++) acc[c] = bf2f(sv[c]);   // self: dinv[node]*x[node]
      int o0 = offs[node], cnt = deg[node] - 1;
      for(int jb = 0; jb < cnt; jb += 8){
        int rux[8]; float wk[8];
        #pragma unroll
        for(int k = 0; k < 8; k++){
          int jj = jb + k;
          bool ok = jj < cnt;
          rux[k] = srcs[o0 + (ok ? jj : cnt-1)];
          wk[k] = ok ? 1.f : 0.f;
        }
        #pragma unroll
        for(int k = 0; k < 8; k++){
          bf16x8 v = *(const bf16x8*)(xs + (long)rux[k]*DD + lane16*8);
          float wkk = wk[k];
          #pragma unroll
          for(int c = 0; c < 8; c++) acc[c] += bf2f(v[c])*wkk;
        }
      }
      #pragma unroll
      for(int c = 0; c < 8; c++) acc[c] *= di;
    }
    u32x4 o8;
    #pragma unroll
    for(int k = 0; k < 4; k++) o8[k] = cvt_pk_bf16(acc[2*k], acc[2*k+1]);
    int byte = row*256 + ((lane16*16) ^ ((row&7)<<4));
    *(u32x4*)(Alds + byte) = o8;
  }
  __syncthreads();
  // ---- GEMM ----
  f32x4 acc[4][2];
  #pragma unroll
  for(int m = 0; m < 4; m++) for(int j = 0; j < 2; j++) acc[m][j] = (f32x4){0,0,0,0};
  #pragma unroll
  for(int ks = 0; ks < 4; ks++){
    bf16x8 af[4];
    #pragma unroll
    for(int m = 0; m < 4; m++){
      int r = m*16 + lrow;
      int byte = r*256 + ((ks*64 + lk*16) ^ ((r&7)<<4));
      af[m] = *(const bf16x8*)(Alds + byte);
    }
    #pragma unroll
    for(int j = 0; j < 2; j++)
      #pragma unroll
      for(int m = 0; m < 4; m++)
        acc[m][j] = __builtin_amdgcn_mfma_f32_16x16x32_bf16(af[m], Bg[j][ks], acc[m][j], 0,0,0);
  }
  #pragma unroll
  for(int j = 0; j < 2; j++){
    int col = (w*2+j)*16 + lrow;
    float bv = bias[col];
    float s = 0.f, s2 = 0.f;
    #pragma unroll
    for(int m = 0; m < 4; m++){
      int rb = row0 + m*16 + lk*4;
      #pragma unroll
      for(int rr = 0; rr < 4; rr += 2){
        int rowA = rb + rr, rowB = rb + rr + 1;
        float hA = acc[m][j][rr] + bv;
        float hB = acc[m][j][rr+1] + bv;
        uint32_t u = cvt_pk_bf16(hA, hB);
        if(rowA < n){ hraw[(long)rowA*DD + col] = (short)(u & 0xffff); s += hA; s2 += hA*hA; }
        if(rowB < n){ hraw[(long)rowB*DD + col] = (short)(u >> 16);   s += hB; s2 += hB*hB; }
      }
    }
    s  += __shfl_xor(s, 16);  s  += __shfl_xor(s, 32);
    s2 += __shfl_xor(s2, 16); s2 += __shfl_xor(s2, 32);
    if(lk == 0){
      atomicAdd(&sum[col], s);
      atomicAdd(&sumsq[col], s2);
    }
  }
}

// ---------------- fused GRU: M=64 (2 pipelined 32-row tiles), lgkm-only barriers ----
// Tile1 stage loads issued during tile0's gates/HT/epilogue; barriers never drain vmcnt.

__device__ __forceinline__ void gru_stage_issue(const short* hraw, const short* Hb,
    int rowbase, int t, int n, u32x4* sreg){
  #pragma unroll
  for(int i = 0; i < 4; i++){
    int u = t + i*256;
    int r = u >> 5, ku = u & 31;
    int grow = rowbase + r;
    u32x4 o = {0,0,0,0};
    if(grow < n){
      if(ku < 16) o = *(const u32x4*)(hraw + (long)grow*DD + ku*8);
      else        o = *(const u32x4*)(Hb + (long)grow*DD + (ku-16)*8);
    }
    sreg[i] = o;
  }
}

__device__ __forceinline__ void gru_stage_convert(char* Alds, const u32x4* sreg,
    const float* sSc, const float* sSh, float pa, int t){
  #pragma unroll
  for(int i = 0; i < 4; i++){
    int u = t + i*256;
    int r = u >> 5, ku = u & 31;
    u32x4 o = sreg[i];
    if(ku < 16){
      float f[8];
      #pragma unroll
      for(int j = 0; j < 8; j++){
        int c = ku*8 + j;
        short hv = (short)((o[j>>1] >> ((j&1)*16)) & 0xffff);
        float v = bf2f(hv)*sSc[c] + sSh[c];
        f[j] = v > 0.f ? v : pa*v;
      }
      #pragma unroll
      for(int k2 = 0; k2 < 4; k2++) o[k2] = cvt_pk_bf16(f[2*k2], f[2*k2+1]);
    }
    int byte = r*512 + ((ku*16) ^ ((r&7)<<4));
    *(u32x4*)(Alds + byte) = o;
  }
}

template<bool NEXT>
__device__ __forceinline__ void gru_tile(char* Alds, char* RHl,
    const short* bbZR, const short* bbHT,
    const float* bz, const float* br, const float* bh,
    const short* hraw, const short* Hb, float* out,
    int row0t, int nextbase, u32x4* sreg, bf16x8 (&cur)[2][4],
    int t, int w, int lrow, int lk, int n){
  bf16x8 nxt[2][4];
  // ---- ZR GEMM: 4 passes of (2 cols x 4 ks), cur holds pass0 ----
  f32x4 acc[2][4];
  #pragma unroll
  for(int m = 0; m < 2; m++) for(int j = 0; j < 4; j++) acc[m][j] = (f32x4){0,0,0,0};
  #pragma unroll
  for(int p = 0; p < 4; p++){
    const int jh = p >> 1, kh = p & 1;
    if(p < 3){
      const int pn = p + 1, jn = pn >> 1, kn = pn & 1;
      #pragma unroll
      for(int j = 0; j < 2; j++)
        #pragma unroll
        for(int ks = 0; ks < 4; ks++)
          nxt[j][ks] = *(const bf16x8*)(bbZR + (jn*2+j)*4096 + (kn*4+ks)*32);
    }
    #pragma unroll
    for(int ks = 0; ks < 4; ks++){
      const int ksg = kh*4 + ks;
      bf16x8 af[2];
      #pragma unroll
      for(int m = 0; m < 2; m++){
        int r = m*16 + lrow;
        af[m] = *(const bf16x8*)(Alds + r*512 + ((ksg*64 + lk*16) ^ ((r&7)<<4)));
      }
      #pragma unroll
      for(int j = 0; j < 2; j++)
        #pragma unroll
        for(int m = 0; m < 2; m++)
          acc[m][jh*2+j] = __builtin_amdgcn_mfma_f32_16x16x32_bf16(af[m], cur[j][ks], acc[m][jh*2+j], 0,0,0);
    }
    if(p < 3){
      #pragma unroll
      for(int j = 0; j < 2; j++)
        #pragma unroll
        for(int ks = 0; ks < 4; ks++)
          cur[j][ks] = nxt[j][ks];
    }
  }
  // ---- issue next tile's stage loads (fly under gates + HT + epilogue) ----
  if(NEXT) gru_stage_issue(hraw, Hb, nextbase, t, n, sreg);
  // ---- issue HT pass-0 B loads (fly during gates) ----
  #pragma unroll
  for(int j = 0; j < 2; j++)
    #pragma unroll
    for(int ks = 0; ks < 4; ks++)
      cur[j][ks] = *(const bf16x8*)(bbHT + j*4096 + ks*32);
  // ---- gates: j 0-1 -> Z in registers; j 2-3 -> R*H -> RHl ----
  float zreg[2][2][4];
  #pragma unroll
  for(int j = 0; j < 2; j++){
    int col = w*32 + j*16 + lrow;
    float bv = bz[col];
    #pragma unroll
    for(int m = 0; m < 2; m++)
      #pragma unroll
      for(int rr = 0; rr < 4; rr++)
        zreg[j][m][rr] = sigm(acc[m][j][rr] + bv);
  }
  #pragma unroll
  for(int j = 2; j < 4; j++){
    int colR = w*32 + (j-2)*16 + lrow;
    int col256 = 128 + colR;
    float bv = br[colR];
    #pragma unroll
    for(int m = 0; m < 2; m++){
      #pragma unroll
      for(int rr = 0; rr < 4; rr += 2){
        int rowA = m*16 + lk*4 + rr, rowB = rowA + 1;
        int hbA = rowA*512 + ((2*col256) ^ ((rowA&7)<<4));
        int hbB = rowB*512 + ((2*col256) ^ ((rowB&7)<<4));
        float rhA = sigm(acc[m][j][rr] + bv)   * bf2f(*(const short*)(Alds + hbA));
        float rhB = sigm(acc[m][j][rr+1] + bv) * bf2f(*(const short*)(Alds + hbB));
        uint32_t u2 = cvt_pk_bf16(rhA, rhB);
        int obA = rowA*256 + ((2*colR) ^ ((rowA&7)<<4));
        int obB = rowB*256 + ((2*colR) ^ ((rowB&7)<<4));
        *(short*)(RHl + obA) = (short)(u2 & 0xffff);
        *(short*)(RHl + obB) = (short)(u2 >> 16);
      }
    }
  }
  LGKM_BAR();   // RHl visible; stage/B loads stay in flight
  // ---- HT GEMM: 2 passes; K 0-127 Alds(h), 128-255 RHl ----
  f32x4 acc2[2][2];
  #pragma unroll
  for(int m = 0; m < 2; m++) for(int j = 0; j < 2; j++) acc2[m][j] = (f32x4){0,0,0,0};
  #pragma unroll
  for(int p = 0; p < 2; p++){
    if(p < 1){
      #pragma unroll
      for(int j = 0; j < 2; j++)
        #pragma unroll
        for(int ks = 0; ks < 4; ks++)
          nxt[j][ks] = *(const bf16x8*)(bbHT + j*4096 + (4+ks)*32);
    }
    #pragma unroll
    for(int ks = 0; ks < 4; ks++){
      const int ksg = p*4 + ks;
      bf16x8 af[2];
      #pragma unroll
      for(int m = 0; m < 2; m++){
        int r = m*16 + lrow;
        if(ksg < 4)
          af[m] = *(const bf16x8*)(Alds + r*512 + ((ksg*64 + lk*16) ^ ((r&7)<<4)));
        else
          af[m] = *(const bf16x8*)(RHl + r*256 + (((ksg-4)*64 + lk*16) ^ ((r&7)<<4)));
      }
      #pragma unroll
      for(int j = 0; j < 2; j++)
        #pragma unroll
        for(int m = 0; m < 2; m++)
          acc2[m][j] = __builtin_amdgcn_mfma_f32_16x16x32_bf16(af[m], cur[j][ks], acc2[m][j], 0,0,0);
    }
    if(p < 1){
      #pragma unroll
      for(int j = 0; j < 2; j++)
        #pragma unroll
        for(int ks = 0; ks < 4; ks++)
          cur[j][ks] = nxt[j][ks];
    }
  }
  // ---- epilogue: out = z*H + (1-z)*tanh(ht) ----
  #pragma unroll
  for(int j = 0; j < 2; j++){
    int col = w*32 + j*16 + lrow;
    float bv = bh[col];
    #pragma unroll
    for(int m = 0; m < 2; m++){
      #pragma unroll
      for(int rr = 0; rr < 4; rr++){
        int row = m*16 + lk*4 + rr;
        int grow = row0t + row;
        if(grow < n){
          float ht = tanh_f(acc2[m][j][rr] + bv);
          float z = zreg[j][m][rr];
          int hb = row*512 + ((2*(128+col)) ^ ((row&7)<<4));
          float Hv = bf2f(*(const short*)(Alds + hb));
          out[(long)grow*DD + col] = z*Hv + (1.f - z)*ht;
        }
      }
    }
  }
  // ---- reload ZR pass-0 B for the next tile (L2-hot; hidden under convert) ----
  if(NEXT){
    #pragma unroll
    for(int j = 0; j < 2; j++)
      #pragma unroll
      for(int ks = 0; ks < 4; ks++)
        cur[j][ks] = *(const bf16x8*)(bbZR + j*4096 + ks*32);
  }
}

__global__ __launch_bounds__(256) void gru_k(const short* hraw, const short* Hb,
    const short* wtzr, const short* wth, const float* sum, const float* sumsq,
    const float* gamma, const float* beta, const float* prelu,
    const float* bz, const float* br, const float* bh, float* out, int n){
  __shared__ char Alds[32*512];
  __shared__ char RHl[32*256];
  __shared__ float sSc[128], sSh[128];
  const int t = threadIdx.x;
  const int row0 = blockIdx.x*64;
  const float pa = prelu[0];
  const int w = t >> 6, l = t & 63;
  const int lrow = l & 15, lk = l >> 4;
  const short* bbZR = wtzr + (long)(w*64 + lrow)*256 + lk*8;
  const short* bbHT = wth + (long)(w*32 + lrow)*256 + lk*8;

  // ---- issue tile0 stage + ZR pass-0 B loads; BN coeffs while they fly ----
  u32x4 sreg[4];
  gru_stage_issue(hraw, Hb, row0, t, n, sreg);
  bf16x8 cur[2][4];
  #pragma unroll
  for(int j = 0; j < 2; j++)
    #pragma unroll
    for(int ks = 0; ks < 4; ks++)
      cur[j][ks] = *(const bf16x8*)(bbZR + j*4096 + ks*32);
  if(t < 128){
    float inv_n = 1.0f/(float)n;
    float mean = sum[t]*inv_n;
    float var = sumsq[t]*inv_n - mean*mean;
    float sc = gamma[t]*rsqrtf(var + 1e-5f);
    sSc[t] = sc; sSh[t] = beta[t] - mean*sc;
  }
  LGKM_BAR();                                  // BN coeffs visible
  gru_stage_convert(Alds, sreg, sSc, sSh, pa, t);
  LGKM_BAR();                                  // Alds(T0) visible

  // ---- tile 0 (also issues tile1 stage + reloads ZR B) ----
  gru_tile<true>(Alds, RHl, bbZR, bbHT, bz, br, bh, hraw, Hb, out,
                 row0, row0 + 32, sreg, cur, t, w, lrow, lk, n);
  LGKM_BAR();                                  // all T0 reads of Alds/RHl done
  gru_stage_convert(Alds, sreg, sSc, sSh, pa, t);
  LGKM_BAR();                                  // Alds(T1) visible

  // ---- tile 1 ----
  gru_tile<false>(Alds, RHl, bbZR, bbHT, bz, br, bh, hraw, Hb, out,
                  row0 + 32, 0, sreg, cur, t, w, lrow, lk, n);
}

// ---------------- launch ----------------

extern "C" void kernel_launch(void* const* d_in, const int* in_sizes, int n_in,
                              void* d_out, int out_size, void* d_ws, size_t ws_size,
                              hipStream_t stream){
  const float* x     = (const float*)d_in[0];
  const int*   e32   = (const int*)d_in[1];
  const float* H     = (const float*)d_in[2];
  const float* Wg    = (const float*)d_in[3];
  const float* bg    = (const float*)d_in[4];
  const float* gamma = (const float*)d_in[5];
  const float* beta  = (const float*)d_in[6];
  const float* prelu = (const float*)d_in[7];
  const float* Wz    = (const float*)d_in[8];
  const float* bz    = (const float*)d_in[9];
  const float* Wr    = (const float*)d_in[10];
  const float* br    = (const float*)d_in[11];
  const float* Wh    = (const float*)d_in[12];
  const float* bh    = (const float*)d_in[13];
  float* out = (float*)d_out;
  const int n = in_sizes[0] / DD;
  const int e = in_sizes[1] / 2;
  const int nb = (n + CHUNK - 1) / CHUNK;

  char* ws = (char*)d_ws;
  size_t o = 0;
  auto alloc = [&](size_t bytes)->char*{
    char* p = ws + o; o = (o + bytes + 255) & ~(size_t)255; return p;
  };
  int*   deg    = (int*)  alloc(4L*n);
  float* dinv   = (float*)alloc(4L*n);
  int*   flag   = (int*)  alloc(256);   // flag+sum+sumsq contiguous: one memset
  float* sum    = (float*)alloc(512);
  float* sumsq  = (float*)alloc(512);
  int*   bsum   = (int*)  alloc(4L*nb);
  int*   offs   = (int*)  alloc(4L*n);
  int*   cursor = (int*)  alloc(4L*n);
  int*   srcs   = (int*)  alloc(4L*e);
  short* wtg    = (short*)alloc(128L*128*2);
  short* wtzr   = (short*)alloc(256L*256*2);
  short* wth    = (short*)alloc(128L*256*2);
  short* hraw   = (short*)alloc(2L*n*DD);
  short* xs     = (short*)alloc(2L*n*DD);
  short* Hb     = (short*)alloc(2L*n*DD);

  hipMemsetAsync(flag, 0, 1280, stream);   // flag + sum + sumsq

  int gi = (n + 255)/256;
  int ge = (e + 255)/256;
  int ginit = gi > ge ? gi : ge;
  if(ginit < 448) ginit = 448;             // cover 114688 weight elements
  init_k<<<ginit, 256, 0, stream>>>(deg, e32, flag, Wg, Wz, Wr, Wh, wtg, wtzr, wth, n, e);
  deg_k<<<ge, 256, 0, stream>>>(e32, flag, deg, e, n);
  dscanA_k<<<nb + gi, 256, 0, stream>>>(deg, bsum, dinv, n, nb);
  {
    int cvb = (int)((2L*n*(DD/8) + 255) / 256);
    scanBcvt_k<<<1 + cvb, 256, 0, stream>>>(bsum, nb, x, H, dinv, xs, Hb, n);
  }
  scanC_k<<<nb, 256, 0, stream>>>(deg, bsum, offs, cursor, n);
  fill_k<<<ge, 256, 0, stream>>>(e32, flag, cursor, srcs, e, n);
  gcn_k<<<(n + 63)/64, 256, 0, stream>>>(xs, dinv, offs, deg, srcs, wtg, bg, hraw, sum, sumsq, n);
  gru_k<<<(n + 63)/64, 256, 0, stream>>>(hraw, Hb, wtzr, wth, sum, sumsq, gamma, beta, prelu, bz, br, bh, out, n);
}

// Round 12
// 267.812 us; speedup vs baseline: 1.2468x; 1.2468x over previous
//
#include <hip/hip_runtime.h>
#include <hip/hip_bf16.h>
#include <stdint.h>

#define DD 128
#define CHUNK 1024

typedef short bf16x8 __attribute__((ext_vector_type(8)));
typedef short bf16x4 __attribute__((ext_vector_type(4)));
typedef float f32x4 __attribute__((ext_vector_type(4)));
typedef uint32_t u32x4 __attribute__((ext_vector_type(4)));

__device__ __forceinline__ short f2bf(float f){
  union { float f; uint32_t u; } v; v.f = f;
  uint32_t r = v.u + 0x7fffu + ((v.u >> 16) & 1u);
  return (short)(r >> 16);
}
__device__ __forceinline__ float bf2f(short s){
  union { uint32_t u; float f; } v; v.u = ((uint32_t)(uint16_t)s) << 16;
  return v.f;
}
// packed bf16 convert: lo = bf16(a), hi = bf16(b)  (RNE, hardware)
__device__ __forceinline__ uint32_t cvt_pk_bf16(float a, float b){
  uint32_t r;
  asm("v_cvt_pk_bf16_f32 %0, %1, %2" : "=v"(r) : "v"(a), "v"(b));
  return r;
}
__device__ __forceinline__ float sigm(float x){ return 1.0f/(1.0f + __expf(-x)); }
__device__ __forceinline__ float tanh_f(float x){ return 1.0f - 2.0f/(__expf(2.0f*x) + 1.0f); }

// ---------------- init: deg=1, edge-dtype detect, all weight transposes ----------------
// wtzr column order is wave-interleaved: phys col block [64w,64w+64) =
//   Z logical cols [32w,32w+32) then R logical cols [32w,32w+32).

__global__ __launch_bounds__(256) void init_k(int* deg, const int* e32, int* flag,
    const float* Wg, const float* Wz, const float* Wr, const float* Wh,
    short* wtg, short* wtzr, short* wth, int n, int e){
  int i = blockIdx.x*256 + threadIdx.x;
  if(i < n) deg[i] = 1;                       // self loop
  if(i < e && e32[2*i+1] != 0) *flag = 1;     // int32 storage detected (benign race)
  if(i < 16384){
    int nn = i >> 7, k = i & 127;
    wtg[i] = f2bf(Wg[k*128 + nn]);
  } else if(i < 49152){
    int j = i - 16384; int c = j >> 8, k = j & 255;       // c = Z logical col
    int p = (c >> 5)*64 + (((c >> 4) & 1)*16) + (c & 15); // phys col
    wtzr[p*256 + k] = f2bf(Wz[k*128 + c]);
  } else if(i < 81920){
    int j = i - 49152; int c = j >> 8, k = j & 255;       // c = R logical col
    int p = (c >> 5)*64 + 32 + (((c >> 4) & 1)*16) + (c & 15);
    wtzr[p*256 + k] = f2bf(Wr[k*128 + c]);
  } else if(i < 114688){
    int j = i - 81920; int nn = j >> 8, k = j & 255;
    wth[nn*256 + k] = f2bf(Wh[k*128 + nn]);
  }
}

__device__ __forceinline__ int eidx(const int* e32, int is32, long pos, int n){
  int v = is32 ? e32[pos] : e32[2*pos];
  return v < 0 ? 0 : (v >= n ? n-1 : v);
}

__global__ void deg_k(const int* e32, const int* flag, int* deg, int e, int n){
  int i = blockIdx.x*256 + threadIdx.x;
  if(i >= e) return;
  int is32 = *flag;
  int c = eidx(e32, is32, (long)e + i, n);  // cols = targets
  atomicAdd(&deg[c], 1);
}

// ---------------- scanA (per-chunk sums) + dinv, merged ----------------

__global__ __launch_bounds__(256) void dscanA_k(const int* deg, int* bsum,
                                                float* dinv, int n, int nb){
  int t = threadIdx.x;
  if((int)blockIdx.x < nb){
    __shared__ int ls[256];
    int b = blockIdx.x;
    int base = b*CHUNK + t*4;
    int s = 0;
    #pragma unroll
    for(int j = 0; j < 4; j++){ int i = base + j; if(i < n) s += deg[i] - 1; }
    ls[t] = s; __syncthreads();
    for(int off = 128; off > 0; off >>= 1){
      if(t < off) ls[t] += ls[t+off];
      __syncthreads();
    }
    if(t == 0) bsum[b] = ls[0];
  } else {
    int i = (blockIdx.x - nb)*256 + t;
    if(i < n) dinv[i] = rsqrtf((float)deg[i]);
  }
}

// ---------------- scanB (parallel exclusive scan of bsum) + cvtxh, merged ----------

__global__ __launch_bounds__(256) void scanBcvt_k(int* bsum, int nb,
    const float* x, const float* H, const float* dinv, short* xs, short* Hb, int n){
  int t = threadIdx.x;
  if(blockIdx.x == 0){
    if(nb <= 256){
      __shared__ int ls[256];
      int v = (t < nb) ? bsum[t] : 0;
      ls[t] = v; __syncthreads();
      for(int d = 1; d < 256; d <<= 1){
        int tmp = (t >= d) ? ls[t-d] : 0;
        __syncthreads();
        ls[t] += tmp;
        __syncthreads();
      }
      if(t < nb) bsum[t] = ls[t] - v;   // exclusive
    } else if(t == 0){
      int acc = 0;
      for(int i = 0; i < nb; i++){ int v = bsum[i]; bsum[i] = acc; acc += v; }
    }
  } else {
    long i = (long)(blockIdx.x - 1)*256 + t;
    long tot = (long)n*(DD/8);
    if(i >= 2*tot) return;
    bool isH = i >= tot;
    long j = isH ? i - tot : i;
    const float* src = isH ? H : x;
    f32x4 a = *(const f32x4*)(src + j*8);
    f32x4 b = *(const f32x4*)(src + j*8 + 4);
    float sc = isH ? 1.f : dinv[(int)(j >> 4)];
    u32x4 o;
    o[0] = cvt_pk_bf16(a[0]*sc, a[1]*sc);
    o[1] = cvt_pk_bf16(a[2]*sc, a[3]*sc);
    o[2] = cvt_pk_bf16(b[0]*sc, b[1]*sc);
    o[3] = cvt_pk_bf16(b[2]*sc, b[3]*sc);
    *(u32x4*)((isH ? Hb : xs) + j*8) = o;
  }
}

__global__ __launch_bounds__(256) void scanC_k(const int* deg, const int* bsum,
                                               int* off, int* cursor, int n){
  __shared__ int ls[256];
  int b = blockIdx.x, t = threadIdx.x;
  int base = b*CHUNK + t*4;
  int v[4]; int s = 0;
  #pragma unroll
  for(int j = 0; j < 4; j++){ int i = base + j; v[j] = (i < n) ? deg[i]-1 : 0; s += v[j]; }
  ls[t] = s; __syncthreads();
  for(int d = 1; d < 256; d <<= 1){
    int tmp = (t >= d) ? ls[t-d] : 0;
    __syncthreads();
    ls[t] += tmp;
    __syncthreads();
  }
  int run = bsum[b] + ls[t] - s;   // exclusive prefix
  #pragma unroll
  for(int j = 0; j < 4; j++){
    int i = base + j;
    if(i < n){ off[i] = run; cursor[i] = run; run += v[j]; }
  }
}

__global__ void fill_k(const int* e32, const int* flag, int* cursor, int* srcs,
                       int e, int n){
  int i = blockIdx.x*256 + threadIdx.x;
  if(i >= e) return;
  int is32 = *flag;
  int r = eidx(e32, is32, i, n);
  int c = eidx(e32, is32, (long)e + i, n);
  int slot = atomicAdd(&cursor[c], 1);
  srcs[slot] = r;
}

// ---------------- fused GCN: CSR gather (bf16, pre-scaled) -> LDS -> GEMM ----------

__global__ __launch_bounds__(256) void gcn_k(const short* xs, const float* dinv,
    const int* offs, const int* deg, const int* srcs, const short* wt,
    const float* bias, short* hraw, float* sum, float* sumsq, int n){
  __shared__ char Alds[64*256];  // 64 rows x 128 bf16, XOR-swizzled
  const int t = threadIdx.x;
  const int row0 = blockIdx.x*64;
  const int w = t >> 6, ll = t & 63;
  const int lrow = ll & 15, lk = ll >> 4;
  // ---- preload all B fragments (independent of everything) ----
  bf16x8 Bg[2][4];
  #pragma unroll
  for(int j = 0; j < 2; j++){
    int col = (w*2+j)*16 + lrow;
    #pragma unroll
    for(int ks = 0; ks < 4; ks++)
      Bg[j][ks] = *(const bf16x8*)(wt + col*128 + ks*32 + lk*8);
  }
  // ---- gather ----
  const int g = t >> 4, lane16 = t & 15;
  for(int rr = 0; rr < 4; rr++){
    int row = g*4 + rr;
    int node = row0 + row;
    float acc[8] = {0,0,0,0,0,0,0,0};
    if(node < n){
      float di = dinv[node];
      bf16x8 sv = *(const bf16x8*)(xs + (long)node*DD + lane16*8);
      #pragma unroll
      for(int c = 0; c < 8; c++) acc[c] = bf2f(sv[c]);   // self: dinv[node]*x[node]
      int o0 = offs[node], cnt = deg[node] - 1;
      for(int jb = 0; jb < cnt; jb += 8){
        int rux[8]; float wk[8];
        #pragma unroll
        for(int k = 0; k < 8; k++){
          int jj = jb + k;
          bool ok = jj < cnt;
          rux[k] = srcs[o0 + (ok ? jj : cnt-1)];
          wk[k] = ok ? 1.f : 0.f;
        }
        #pragma unroll
        for(int k = 0; k < 8; k++){
          bf16x8 v = *(const bf16x8*)(xs + (long)rux[k]*DD + lane16*8);
          float wkk = wk[k];
          #pragma unroll
          for(int c = 0; c < 8; c++) acc[c] += bf2f(v[c])*wkk;
        }
      }
      #pragma unroll
      for(int c = 0; c < 8; c++) acc[c] *= di;
    }
    u32x4 o8;
    #pragma unroll
    for(int k = 0; k < 4; k++) o8[k] = cvt_pk_bf16(acc[2*k], acc[2*k+1]);
    int byte = row*256 + ((lane16*16) ^ ((row&7)<<4));
    *(u32x4*)(Alds + byte) = o8;
  }
  __syncthreads();
  // ---- GEMM ----
  f32x4 acc[4][2];
  #pragma unroll
  for(int m = 0; m < 4; m++) for(int j = 0; j < 2; j++) acc[m][j] = (f32x4){0,0,0,0};
  #pragma unroll
  for(int ks = 0; ks < 4; ks++){
    bf16x8 af[4];
    #pragma unroll
    for(int m = 0; m < 4; m++){
      int r = m*16 + lrow;
      int byte = r*256 + ((ks*64 + lk*16) ^ ((r&7)<<4));
      af[m] = *(const bf16x8*)(Alds + byte);
    }
    #pragma unroll
    for(int j = 0; j < 2; j++)
      #pragma unroll
      for(int m = 0; m < 4; m++)
        acc[m][j] = __builtin_amdgcn_mfma_f32_16x16x32_bf16(af[m], Bg[j][ks], acc[m][j], 0,0,0);
  }
  #pragma unroll
  for(int j = 0; j < 2; j++){
    int col = (w*2+j)*16 + lrow;
    float bv = bias[col];
    float s = 0.f, s2 = 0.f;
    #pragma unroll
    for(int m = 0; m < 4; m++){
      int rb = row0 + m*16 + lk*4;
      #pragma unroll
      for(int rr = 0; rr < 4; rr += 2){
        int rowA = rb + rr, rowB = rb + rr + 1;
        float hA = acc[m][j][rr] + bv;
        float hB = acc[m][j][rr+1] + bv;
        uint32_t u = cvt_pk_bf16(hA, hB);
        if(rowA < n){ hraw[(long)rowA*DD + col] = (short)(u & 0xffff); s += hA; s2 += hA*hA; }
        if(rowB < n){ hraw[(long)rowB*DD + col] = (short)(u >> 16);   s += hB; s2 += hB*hB; }
      }
    }
    s  += __shfl_xor(s, 16);  s  += __shfl_xor(s, 32);
    s2 += __shfl_xor(s2, 16); s2 += __shfl_xor(s2, 32);
    if(lk == 0){
      atomicAdd(&sum[col], s);
      atomicAdd(&sumsq[col], s2);
    }
  }
}

// ---------------- fused GRU: M=32, Z-in-registers, VGPR<=64 (8 waves/SIMD) ----------
// wtzr phys col block [64w,64w+64) = Z[32w..+32) | R[32w..+32)  (init_k reorder).
// B loads chunked 2-ks at a time (16 VGPR) instead of pass-ahead double-buffer:
// trade ILP for TLP — the <=64 VGPR slot doubles resident waves (m69 quantum).

__global__ __launch_bounds__(256, 8) void gru_k(const short* hraw, const short* Hb,
    const short* wtzr, const short* wth, const float* sum, const float* sumsq,
    const float* gamma, const float* beta, const float* prelu,
    const float* bz, const float* br, const float* bh, float* out, int n){
  __shared__ char Alds[32*512];
  __shared__ char RHl[32*256];
  __shared__ float sSc[128], sSh[128];
  const int t = threadIdx.x;
  const int row0 = blockIdx.x*32;
  const float pa = prelu[0];
  const int w = t >> 6, l = t & 63;
  const int lrow = l & 15, lk = l >> 4;
  const short* bbZR = wtzr + (long)(w*64 + lrow)*256 + lk*8;
  const short* bbHT = wth + (long)(w*32 + lrow)*256 + lk*8;

  // ---- issue stage loads (4 x 16B per thread, all bf16) ----
  u32x4 sreg[4];
  #pragma unroll
  for(int i = 0; i < 4; i++){
    int u = t + i*256;
    int r = u >> 5, ku = u & 31;
    int grow = row0 + r;
    u32x4 o = {0,0,0,0};
    if(grow < n){
      if(ku < 16) o = *(const u32x4*)(hraw + (long)grow*DD + ku*8);
      else        o = *(const u32x4*)(Hb + (long)grow*DD + (ku-16)*8);
    }
    sreg[i] = o;
  }
  // BN coeffs while loads fly
  if(t < 128){
    float inv_n = 1.0f/(float)n;
    float mean = sum[t]*inv_n;
    float var = sumsq[t]*inv_n - mean*mean;
    float sc = gamma[t]*rsqrtf(var + 1e-5f);
    sSc[t] = sc; sSh[t] = beta[t] - mean*sc;
  }
  __syncthreads();
  // convert + write LDS
  #pragma unroll
  for(int i = 0; i < 4; i++){
    int u = t + i*256;
    int r = u >> 5, ku = u & 31;
    u32x4 o = sreg[i];
    if(ku < 16){
      float f[8];
      #pragma unroll
      for(int j = 0; j < 8; j++){
        int c = ku*8 + j;
        short hv = (short)((o[j>>1] >> ((j&1)*16)) & 0xffff);
        float v = bf2f(hv)*sSc[c] + sSh[c];
        f[j] = v > 0.f ? v : pa*v;
      }
      #pragma unroll
      for(int k2 = 0; k2 < 4; k2++) o[k2] = cvt_pk_bf16(f[2*k2], f[2*k2+1]);
    }
    int byte = r*512 + ((ku*16) ^ ((r&7)<<4));
    *(u32x4*)(Alds + byte) = o;
  }
  __syncthreads();

  // ---- ZR GEMM: jh-major; B loaded in 2-ks chunks (16 VGPR live) ----
  f32x4 acc[2][4];
  #pragma unroll
  for(int m = 0; m < 2; m++) for(int j = 0; j < 4; j++) acc[m][j] = (f32x4){0,0,0,0};
  #pragma unroll
  for(int jh = 0; jh < 2; jh++){
    #pragma unroll
    for(int kc = 0; kc < 4; kc++){
      bf16x8 cb[2][2];
      #pragma unroll
      for(int j = 0; j < 2; j++)
        #pragma unroll
        for(int k2 = 0; k2 < 2; k2++)
          cb[j][k2] = *(const bf16x8*)(bbZR + (jh*2+j)*4096 + (kc*2+k2)*32);
      #pragma unroll
      for(int k2 = 0; k2 < 2; k2++){
        const int ksg = kc*2 + k2;
        bf16x8 af[2];
        #pragma unroll
        for(int m = 0; m < 2; m++){
          int r = m*16 + lrow;
          af[m] = *(const bf16x8*)(Alds + r*512 + ((ksg*64 + lk*16) ^ ((r&7)<<4)));
        }
        #pragma unroll
        for(int j = 0; j < 2; j++)
          #pragma unroll
          for(int m = 0; m < 2; m++)
            acc[m][jh*2+j] = __builtin_amdgcn_mfma_f32_16x16x32_bf16(af[m], cb[j][k2], acc[m][jh*2+j], 0,0,0);
      }
    }
  }

  // ---- gates: j 0-1 -> Z in registers; j 2-3 -> R*H -> RHl ----
  float zreg[2][2][4];
  #pragma unroll
  for(int j = 0; j < 2; j++){
    int col = w*32 + j*16 + lrow;       // Z logical col (matches HT/epilogue col)
    float bv = bz[col];
    #pragma unroll
    for(int m = 0; m < 2; m++)
      #pragma unroll
      for(int rr = 0; rr < 4; rr++)
        zreg[j][m][rr] = sigm(acc[m][j][rr] + bv);
  }
  #pragma unroll
  for(int j = 2; j < 4; j++){
    int colR = w*32 + (j-2)*16 + lrow;  // R logical col
    int col256 = 128 + colR;
    float bv = br[colR];
    #pragma unroll
    for(int m = 0; m < 2; m++){
      #pragma unroll
      for(int rr = 0; rr < 4; rr += 2){
        int rowA = m*16 + lk*4 + rr, rowB = rowA + 1;
        int hbA = rowA*512 + ((2*col256) ^ ((rowA&7)<<4));
        int hbB = rowB*512 + ((2*col256) ^ ((rowB&7)<<4));
        float rhA = sigm(acc[m][j][rr] + bv)   * bf2f(*(const short*)(Alds + hbA));
        float rhB = sigm(acc[m][j][rr+1] + bv) * bf2f(*(const short*)(Alds + hbB));
        uint32_t u2 = cvt_pk_bf16(rhA, rhB);
        int obA = rowA*256 + ((2*colR) ^ ((rowA&7)<<4));
        int obB = rowB*256 + ((2*colR) ^ ((rowB&7)<<4));
        *(short*)(RHl + obA) = (short)(u2 & 0xffff);
        *(short*)(RHl + obB) = (short)(u2 >> 16);
      }
    }
  }
  __syncthreads();

  // ---- HT GEMM: K 0-127 Alds(h), 128-255 RHl; B in 2-ks chunks ----
  f32x4 acc2[2][2];
  #pragma unroll
  for(int m = 0; m < 2; m++) for(int j = 0; j < 2; j++) acc2[m][j] = (f32x4){0,0,0,0};
  #pragma unroll
  for(int kc = 0; kc < 4; kc++){
    bf16x8 cb[2][2];
    #pragma unroll
    for(int j = 0; j < 2; j++)
      #pragma unroll
      for(int k2 = 0; k2 < 2; k2++)
        cb[j][k2] = *(const bf16x8*)(bbHT + j*4096 + (kc*2+k2)*32);
    #pragma unroll
    for(int k2 = 0; k2 < 2; k2++){
      const int ksg = kc*2 + k2;
      bf16x8 af[2];
      #pragma unroll
      for(int m = 0; m < 2; m++){
        int r = m*16 + lrow;
        if(ksg < 4)
          af[m] = *(const bf16x8*)(Alds + r*512 + ((ksg*64 + lk*16) ^ ((r&7)<<4)));
        else
          af[m] = *(const bf16x8*)(RHl + r*256 + (((ksg-4)*64 + lk*16) ^ ((r&7)<<4)));
      }
      #pragma unroll
      for(int j = 0; j < 2; j++)
        #pragma unroll
        for(int m = 0; m < 2; m++)
          acc2[m][j] = __builtin_amdgcn_mfma_f32_16x16x32_bf16(af[m], cb[j][k2], acc2[m][j], 0,0,0);
    }
  }

  // ---- epilogue: out = z*H + (1-z)*tanh(ht);  z from zreg, H from LDS ----
  #pragma unroll
  for(int j = 0; j < 2; j++){
    int col = w*32 + j*16 + lrow;
    float bv = bh[col];
    #pragma unroll
    for(int m = 0; m < 2; m++){
      #pragma unroll
      for(int rr = 0; rr < 4; rr++){
        int row = m*16 + lk*4 + rr;
        int grow = row0 + row;
        if(grow < n){
          float ht = tanh_f(acc2[m][j][rr] + bv);
          float z = zreg[j][m][rr];
          int hb = row*512 + ((2*(128+col)) ^ ((row&7)<<4));
          float Hv = bf2f(*(const short*)(Alds + hb));
          out[(long)grow*DD + col] = z*Hv + (1.f - z)*ht;
        }
      }
    }
  }
}

// ---------------- launch ----------------

extern "C" void kernel_launch(void* const* d_in, const int* in_sizes, int n_in,
                              void* d_out, int out_size, void* d_ws, size_t ws_size,
                              hipStream_t stream){
  const float* x     = (const float*)d_in[0];
  const int*   e32   = (const int*)d_in[1];
  const float* H     = (const float*)d_in[2];
  const float* Wg    = (const float*)d_in[3];
  const float* bg    = (const float*)d_in[4];
  const float* gamma = (const float*)d_in[5];
  const float* beta  = (const float*)d_in[6];
  const float* prelu = (const float*)d_in[7];
  const float* Wz    = (const float*)d_in[8];
  const float* bz    = (const float*)d_in[9];
  const float* Wr    = (const float*)d_in[10];
  const float* br    = (const float*)d_in[11];
  const float* Wh    = (const float*)d_in[12];
  const float* bh    = (const float*)d_in[13];
  float* out = (float*)d_out;
  const int n = in_sizes[0] / DD;
  const int e = in_sizes[1] / 2;
  const int nb = (n + CHUNK - 1) / CHUNK;

  char* ws = (char*)d_ws;
  size_t o = 0;
  auto alloc = [&](size_t bytes)->char*{
    char* p = ws + o; o = (o + bytes + 255) & ~(size_t)255; return p;
  };
  int*   deg    = (int*)  alloc(4L*n);
  float* dinv   = (float*)alloc(4L*n);
  int*   flag   = (int*)  alloc(256);   // flag+sum+sumsq contiguous: one memset
  float* sum    = (float*)alloc(512);
  float* sumsq  = (float*)alloc(512);
  int*   bsum   = (int*)  alloc(4L*nb);
  int*   offs   = (int*)  alloc(4L*n);
  int*   cursor = (int*)  alloc(4L*n);
  int*   srcs   = (int*)  alloc(4L*e);
  short* wtg    = (short*)alloc(128L*128*2);
  short* wtzr   = (short*)alloc(256L*256*2);
  short* wth    = (short*)alloc(128L*256*2);
  short* hraw   = (short*)alloc(2L*n*DD);
  short* xs     = (short*)alloc(2L*n*DD);
  short* Hb     = (short*)alloc(2L*n*DD);

  hipMemsetAsync(flag, 0, 1280, stream);   // flag + sum + sumsq

  int gi = (n + 255)/256;
  int ge = (e + 255)/256;
  int ginit = gi > ge ? gi : ge;
  if(ginit < 448) ginit = 448;             // cover 114688 weight elements
  init_k<<<ginit, 256, 0, stream>>>(deg, e32, flag, Wg, Wz, Wr, Wh, wtg, wtzr, wth, n, e);
  deg_k<<<ge, 256, 0, stream>>>(e32, flag, deg, e, n);
  dscanA_k<<<nb + gi, 256, 0, stream>>>(deg, bsum, dinv, n, nb);
  {
    int cvb = (int)((2L*n*(DD/8) + 255) / 256);
    scanBcvt_k<<<1 + cvb, 256, 0, stream>>>(bsum, nb, x, H, dinv, xs, Hb, n);
  }
  scanC_k<<<nb, 256, 0, stream>>>(deg, bsum, offs, cursor, n);
  fill_k<<<ge, 256, 0, stream>>>(e32, flag, cursor, srcs, e, n);
  gcn_k<<<(n + 63)/64, 256, 0, stream>>>(xs, dinv, offs, deg, srcs, wtg, bg, hraw, sum, sumsq, n);
  gru_k<<<(n + 31)/32, 256, 0, stream>>>(hraw, Hb, wtzr, wth, sum, sumsq, gamma, beta, prelu, bz, br, bh, out, n);
}

// Round 13
// 262.683 us; speedup vs baseline: 1.2711x; 1.0195x over previous
//
#include <hip/hip_runtime.h>
#include <hip/hip_bf16.h>
#include <stdint.h>

#define DD 128
#define CHUNK 1024

typedef short bf16x8 __attribute__((ext_vector_type(8)));
typedef short bf16x4 __attribute__((ext_vector_type(4)));
typedef float f32x4 __attribute__((ext_vector_type(4)));
typedef uint32_t u32x4 __attribute__((ext_vector_type(4)));

__device__ __forceinline__ short f2bf(float f){
  union { float f; uint32_t u; } v; v.f = f;
  uint32_t r = v.u + 0x7fffu + ((v.u >> 16) & 1u);
  return (short)(r >> 16);
}
__device__ __forceinline__ float bf2f(short s){
  union { uint32_t u; float f; } v; v.u = ((uint32_t)(uint16_t)s) << 16;
  return v.f;
}
// packed bf16 convert: lo = bf16(a), hi = bf16(b)  (RNE, hardware)
__device__ __forceinline__ uint32_t cvt_pk_bf16(float a, float b){
  uint32_t r;
  asm("v_cvt_pk_bf16_f32 %0, %1, %2" : "=v"(r) : "v"(a), "v"(b));
  return r;
}
__device__ __forceinline__ float sigm(float x){ return 1.0f/(1.0f + __expf(-x)); }
__device__ __forceinline__ float tanh_f(float x){ return 1.0f - 2.0f/(__expf(2.0f*x) + 1.0f); }

// ---------------- init: deg=1, edge-dtype detect, all weight transposes ----------------
// wtzr column order is wave-interleaved: phys col block [64w,64w+64) =
//   Z logical cols [32w,32w+32) then R logical cols [32w,32w+32).

__global__ __launch_bounds__(256) void init_k(int* deg, const int* e32, int* flag,
    const float* Wg, const float* Wz, const float* Wr, const float* Wh,
    short* wtg, short* wtzr, short* wth, int n, int e){
  int i = blockIdx.x*256 + threadIdx.x;
  if(i < n) deg[i] = 1;                       // self loop
  if(i < e && e32[2*i+1] != 0) *flag = 1;     // int32 storage detected (benign race)
  if(i < 16384){
    int nn = i >> 7, k = i & 127;
    wtg[i] = f2bf(Wg[k*128 + nn]);
  } else if(i < 49152){
    int j = i - 16384; int c = j >> 8, k = j & 255;       // c = Z logical col
    int p = (c >> 5)*64 + (((c >> 4) & 1)*16) + (c & 15); // phys col
    wtzr[p*256 + k] = f2bf(Wz[k*128 + c]);
  } else if(i < 81920){
    int j = i - 49152; int c = j >> 8, k = j & 255;       // c = R logical col
    int p = (c >> 5)*64 + 32 + (((c >> 4) & 1)*16) + (c & 15);
    wtzr[p*256 + k] = f2bf(Wr[k*128 + c]);
  } else if(i < 114688){
    int j = i - 81920; int nn = j >> 8, k = j & 255;
    wth[nn*256 + k] = f2bf(Wh[k*128 + nn]);
  }
}

__device__ __forceinline__ int eidx(const int* e32, int is32, long pos, int n){
  int v = is32 ? e32[pos] : e32[2*pos];
  return v < 0 ? 0 : (v >= n ? n-1 : v);
}

__global__ void deg_k(const int* e32, const int* flag, int* deg, int e, int n){
  int i = blockIdx.x*256 + threadIdx.x;
  if(i >= e) return;
  int is32 = *flag;
  int c = eidx(e32, is32, (long)e + i, n);  // cols = targets
  atomicAdd(&deg[c], 1);
}

// ---------------- scanA (per-chunk sums) + dinv, merged ----------------

__global__ __launch_bounds__(256) void dscanA_k(const int* deg, int* bsum,
                                                float* dinv, int n, int nb){
  int t = threadIdx.x;
  if((int)blockIdx.x < nb){
    __shared__ int ls[256];
    int b = blockIdx.x;
    int base = b*CHUNK + t*4;
    int s = 0;
    #pragma unroll
    for(int j = 0; j < 4; j++){ int i = base + j; if(i < n) s += deg[i] - 1; }
    ls[t] = s; __syncthreads();
    for(int off = 128; off > 0; off >>= 1){
      if(t < off) ls[t] += ls[t+off];
      __syncthreads();
    }
    if(t == 0) bsum[b] = ls[0];
  } else {
    int i = (blockIdx.x - nb)*256 + t;
    if(i < n) dinv[i] = rsqrtf((float)deg[i]);
  }
}

// ---------------- scanB (parallel exclusive scan of bsum) + cvtxh, merged ----------

__global__ __launch_bounds__(256) void scanBcvt_k(int* bsum, int nb,
    const float* x, const float* H, const float* dinv, short* xs, short* Hb, int n){
  int t = threadIdx.x;
  if(blockIdx.x == 0){
    if(nb <= 256){
      __shared__ int ls[256];
      int v = (t < nb) ? bsum[t] : 0;
      ls[t] = v; __syncthreads();
      for(int d = 1; d < 256; d <<= 1){
        int tmp = (t >= d) ? ls[t-d] : 0;
        __syncthreads();
        ls[t] += tmp;
        __syncthreads();
      }
      if(t < nb) bsum[t] = ls[t] - v;   // exclusive
    } else if(t == 0){
      int acc = 0;
      for(int i = 0; i < nb; i++){ int v = bsum[i]; bsum[i] = acc; acc += v; }
    }
  } else {
    long i = (long)(blockIdx.x - 1)*256 + t;
    long tot = (long)n*(DD/8);
    if(i >= 2*tot) return;
    bool isH = i >= tot;
    long j = isH ? i - tot : i;
    const float* src = isH ? H : x;
    f32x4 a = *(const f32x4*)(src + j*8);
    f32x4 b = *(const f32x4*)(src + j*8 + 4);
    float sc = isH ? 1.f : dinv[(int)(j >> 4)];
    u32x4 o;
    o[0] = cvt_pk_bf16(a[0]*sc, a[1]*sc);
    o[1] = cvt_pk_bf16(a[2]*sc, a[3]*sc);
    o[2] = cvt_pk_bf16(b[0]*sc, b[1]*sc);
    o[3] = cvt_pk_bf16(b[2]*sc, b[3]*sc);
    *(u32x4*)((isH ? Hb : xs) + j*8) = o;
  }
}

__global__ __launch_bounds__(256) void scanC_k(const int* deg, const int* bsum,
                                               int* off, int* cursor, int n){
  __shared__ int ls[256];
  int b = blockIdx.x, t = threadIdx.x;
  int base = b*CHUNK + t*4;
  int v[4]; int s = 0;
  #pragma unroll
  for(int j = 0; j < 4; j++){ int i = base + j; v[j] = (i < n) ? deg[i]-1 : 0; s += v[j]; }
  ls[t] = s; __syncthreads();
  for(int d = 1; d < 256; d <<= 1){
    int tmp = (t >= d) ? ls[t-d] : 0;
    __syncthreads();
    ls[t] += tmp;
    __syncthreads();
  }
  int run = bsum[b] + ls[t] - s;   // exclusive prefix
  #pragma unroll
  for(int j = 0; j < 4; j++){
    int i = base + j;
    if(i < n){ off[i] = run; cursor[i] = run; run += v[j]; }
  }
}

__global__ void fill_k(const int* e32, const int* flag, int* cursor, int* srcs,
                       int e, int n){
  int i = blockIdx.x*256 + threadIdx.x;
  if(i >= e) return;
  int is32 = *flag;
  int r = eidx(e32, is32, i, n);
  int c = eidx(e32, is32, (long)e + i, n);
  int slot = atomicAdd(&cursor[c], 1);
  srcs[slot] = r;
}

// ---------------- fused GCN: pipelined CSR gather -> LDS -> GEMM -------------------
// Gather pipeline: phase0 meta+self (12 indep loads), phase1 ALL 32 first-batch srcs
// loads, phase2 per-row xs+FMA (row r+1 loads hoistable above row r FMAs -> 4x MLP).
// B fragments loaded inline in GEMM (saves 32 VGPR for pipeline state).

__global__ __launch_bounds__(256) void gcn_k(const short* xs, const float* dinv,
    const int* offs, const int* deg, const int* srcs, const short* wt,
    const float* bias, short* hraw, float* sum, float* sumsq, int n){
  __shared__ char Alds[64*256];  // 64 rows x 128 bf16, XOR-swizzled
  const int t = threadIdx.x;
  const int row0 = blockIdx.x*64;
  const int w = t >> 6, ll = t & 63;
  const int lrow = ll & 15, lk = ll >> 4;
  const int g = t >> 4, lane16 = t & 15;
  const int gbase = row0 + g*4;

  // ---- phase 0: metadata + self rows (all independent) ----
  float valid[4], di[4];
  int o0[4], cnt[4];
  #pragma unroll
  for(int rr = 0; rr < 4; rr++){
    int node = gbase + rr;
    bool ok = node < n;
    int nc = ok ? node : 0;
    valid[rr] = ok ? 1.f : 0.f;
    di[rr] = dinv[nc];
    o0[rr] = offs[nc];
    cnt[rr] = deg[nc] - 1;
  }
  bf16x8 self[4];
  #pragma unroll
  for(int rr = 0; rr < 4; rr++){
    int node = gbase + rr;
    int nc = node < n ? node : 0;
    self[rr] = *(const bf16x8*)(xs + (long)nc*DD + lane16*8);
  }
  // ---- phase 1: first-batch srcs for all 4 rows (32 loads in flight) ----
  int rux[4][8];
  #pragma unroll
  for(int rr = 0; rr < 4; rr++){
    int c = cnt[rr];
    int base = o0[rr];
    #pragma unroll
    for(int k = 0; k < 8; k++){
      int jj = (k < c) ? k : (c - 1);
      rux[rr][k] = srcs[(c > 0) ? base + jj : 0];
    }
  }
  // ---- phase 2: per-row xs loads + FMA; tail loop for cnt > 8 (rare) ----
  #pragma unroll
  for(int rr = 0; rr < 4; rr++){
    int c = cnt[rr];
    float acc[8];
    #pragma unroll
    for(int q = 0; q < 8; q++) acc[q] = bf2f(self[rr][q]) * valid[rr];
    #pragma unroll
    for(int k = 0; k < 8; k++){
      bf16x8 v = *(const bf16x8*)(xs + (long)rux[rr][k]*DD + lane16*8);
      float wkk = (k < c) ? 1.f : 0.f;
      #pragma unroll
      for(int q = 0; q < 8; q++) acc[q] += bf2f(v[q])*wkk;
    }
    for(int jb = 8; jb < c; jb += 8){
      int r2[8]; float w2[8];
      #pragma unroll
      for(int k = 0; k < 8; k++){
        int jj = jb + k;
        bool ok2 = jj < c;
        r2[k] = srcs[o0[rr] + (ok2 ? jj : c-1)];
        w2[k] = ok2 ? 1.f : 0.f;
      }
      #pragma unroll
      for(int k = 0; k < 8; k++){
        bf16x8 v = *(const bf16x8*)(xs + (long)r2[k]*DD + lane16*8);
        float wkk = w2[k];
        #pragma unroll
        for(int q = 0; q < 8; q++) acc[q] += bf2f(v[q])*wkk;
      }
    }
    u32x4 o8;
    #pragma unroll
    for(int k = 0; k < 4; k++)
      o8[k] = cvt_pk_bf16(acc[2*k]*di[rr], acc[2*k+1]*di[rr]);
    int row = g*4 + rr;
    int byte = row*256 + ((lane16*16) ^ ((row&7)<<4));
    *(u32x4*)(Alds + byte) = o8;
  }
  __syncthreads();
  // ---- GEMM (B inline; one amortized L2 bubble per block) ----
  f32x4 acc[4][2];
  #pragma unroll
  for(int m = 0; m < 4; m++) for(int j = 0; j < 2; j++) acc[m][j] = (f32x4){0,0,0,0};
  #pragma unroll
  for(int ks = 0; ks < 4; ks++){
    bf16x8 af[4];
    #pragma unroll
    for(int m = 0; m < 4; m++){
      int r = m*16 + lrow;
      int byte = r*256 + ((ks*64 + lk*16) ^ ((r&7)<<4));
      af[m] = *(const bf16x8*)(Alds + byte);
    }
    #pragma unroll
    for(int j = 0; j < 2; j++){
      int col = (w*2+j)*16 + lrow;
      bf16x8 bfr = *(const bf16x8*)(wt + col*128 + ks*32 + lk*8);
      #pragma unroll
      for(int m = 0; m < 4; m++)
        acc[m][j] = __builtin_amdgcn_mfma_f32_16x16x32_bf16(af[m], bfr, acc[m][j], 0,0,0);
    }
  }
  #pragma unroll
  for(int j = 0; j < 2; j++){
    int col = (w*2+j)*16 + lrow;
    float bv = bias[col];
    float s = 0.f, s2 = 0.f;
    #pragma unroll
    for(int m = 0; m < 4; m++){
      int rb = row0 + m*16 + lk*4;
      #pragma unroll
      for(int rr = 0; rr < 4; rr += 2){
        int rowA = rb + rr, rowB = rb + rr + 1;
        float hA = acc[m][j][rr] + bv;
        float hB = acc[m][j][rr+1] + bv;
        uint32_t u = cvt_pk_bf16(hA, hB);
        if(rowA < n){ hraw[(long)rowA*DD + col] = (short)(u & 0xffff); s += hA; s2 += hA*hA; }
        if(rowB < n){ hraw[(long)rowB*DD + col] = (short)(u >> 16);   s += hB; s2 += hB*hB; }
      }
    }
    s  += __shfl_xor(s, 16);  s  += __shfl_xor(s, 32);
    s2 += __shfl_xor(s2, 16); s2 += __shfl_xor(s2, 32);
    if(lk == 0){
      atomicAdd(&sum[col], s);
      atomicAdd(&sumsq[col], s2);
    }
  }
}

// ---------------- fused GRU: M=32, Z-in-registers (unchanged from R12) ----------

__global__ __launch_bounds__(256, 8) void gru_k(const short* hraw, const short* Hb,
    const short* wtzr, const short* wth, const float* sum, const float* sumsq,
    const float* gamma, const float* beta, const float* prelu,
    const float* bz, const float* br, const float* bh, float* out, int n){
  __shared__ char Alds[32*512];
  __shared__ char RHl[32*256];
  __shared__ float sSc[128], sSh[128];
  const int t = threadIdx.x;
  const int row0 = blockIdx.x*32;
  const float pa = prelu[0];
  const int w = t >> 6, l = t & 63;
  const int lrow = l & 15, lk = l >> 4;
  const short* bbZR = wtzr + (long)(w*64 + lrow)*256 + lk*8;
  const short* bbHT = wth + (long)(w*32 + lrow)*256 + lk*8;

  // ---- issue stage loads (4 x 16B per thread, all bf16) ----
  u32x4 sreg[4];
  #pragma unroll
  for(int i = 0; i < 4; i++){
    int u = t + i*256;
    int r = u >> 5, ku = u & 31;
    int grow = row0 + r;
    u32x4 o = {0,0,0,0};
    if(grow < n){
      if(ku < 16) o = *(const u32x4*)(hraw + (long)grow*DD + ku*8);
      else        o = *(const u32x4*)(Hb + (long)grow*DD + (ku-16)*8);
    }
    sreg[i] = o;
  }
  // BN coeffs while loads fly
  if(t < 128){
    float inv_n = 1.0f/(float)n;
    float mean = sum[t]*inv_n;
    float var = sumsq[t]*inv_n - mean*mean;
    float sc = gamma[t]*rsqrtf(var + 1e-5f);
    sSc[t] = sc; sSh[t] = beta[t] - mean*sc;
  }
  __syncthreads();
  // convert + write LDS
  #pragma unroll
  for(int i = 0; i < 4; i++){
    int u = t + i*256;
    int r = u >> 5, ku = u & 31;
    u32x4 o = sreg[i];
    if(ku < 16){
      float f[8];
      #pragma unroll
      for(int j = 0; j < 8; j++){
        int c = ku*8 + j;
        short hv = (short)((o[j>>1] >> ((j&1)*16)) & 0xffff);
        float v = bf2f(hv)*sSc[c] + sSh[c];
        f[j] = v > 0.f ? v : pa*v;
      }
      #pragma unroll
      for(int k2 = 0; k2 < 4; k2++) o[k2] = cvt_pk_bf16(f[2*k2], f[2*k2+1]);
    }
    int byte = r*512 + ((ku*16) ^ ((r&7)<<4));
    *(u32x4*)(Alds + byte) = o;
  }
  __syncthreads();

  // ---- ZR GEMM: jh-major; B loaded in 2-ks chunks (16 VGPR live) ----
  f32x4 acc[2][4];
  #pragma unroll
  for(int m = 0; m < 2; m++) for(int j = 0; j < 4; j++) acc[m][j] = (f32x4){0,0,0,0};
  #pragma unroll
  for(int jh = 0; jh < 2; jh++){
    #pragma unroll
    for(int kc = 0; kc < 4; kc++){
      bf16x8 cb[2][2];
      #pragma unroll
      for(int j = 0; j < 2; j++)
        #pragma unroll
        for(int k2 = 0; k2 < 2; k2++)
          cb[j][k2] = *(const bf16x8*)(bbZR + (jh*2+j)*4096 + (kc*2+k2)*32);
      #pragma unroll
      for(int k2 = 0; k2 < 2; k2++){
        const int ksg = kc*2 + k2;
        bf16x8 af[2];
        #pragma unroll
        for(int m = 0; m < 2; m++){
          int r = m*16 + lrow;
          af[m] = *(const bf16x8*)(Alds + r*512 + ((ksg*64 + lk*16) ^ ((r&7)<<4)));
        }
        #pragma unroll
        for(int j = 0; j < 2; j++)
          #pragma unroll
          for(int m = 0; m < 2; m++)
            acc[m][jh*2+j] = __builtin_amdgcn_mfma_f32_16x16x32_bf16(af[m], cb[j][k2], acc[m][jh*2+j], 0,0,0);
      }
    }
  }

  // ---- gates: j 0-1 -> Z in registers; j 2-3 -> R*H -> RHl ----
  float zreg[2][2][4];
  #pragma unroll
  for(int j = 0; j < 2; j++){
    int col = w*32 + j*16 + lrow;       // Z logical col (matches HT/epilogue col)
    float bv = bz[col];
    #pragma unroll
    for(int m = 0; m < 2; m++)
      #pragma unroll
      for(int rr = 0; rr < 4; rr++)
        zreg[j][m][rr] = sigm(acc[m][j][rr] + bv);
  }
  #pragma unroll
  for(int j = 2; j < 4; j++){
    int colR = w*32 + (j-2)*16 + lrow;  // R logical col
    int col256 = 128 + colR;
    float bv = br[colR];
    #pragma unroll
    for(int m = 0; m < 2; m++){
      #pragma unroll
      for(int rr = 0; rr < 4; rr += 2){
        int rowA = m*16 + lk*4 + rr, rowB = rowA + 1;
        int hbA = rowA*512 + ((2*col256) ^ ((rowA&7)<<4));
        int hbB = rowB*512 + ((2*col256) ^ ((rowB&7)<<4));
        float rhA = sigm(acc[m][j][rr] + bv)   * bf2f(*(const short*)(Alds + hbA));
        float rhB = sigm(acc[m][j][rr+1] + bv) * bf2f(*(const short*)(Alds + hbB));
        uint32_t u2 = cvt_pk_bf16(rhA, rhB);
        int obA = rowA*256 + ((2*colR) ^ ((rowA&7)<<4));
        int obB = rowB*256 + ((2*colR) ^ ((rowB&7)<<4));
        *(short*)(RHl + obA) = (short)(u2 & 0xffff);
        *(short*)(RHl + obB) = (short)(u2 >> 16);
      }
    }
  }
  __syncthreads();

  // ---- HT GEMM: K 0-127 Alds(h), 128-255 RHl; B in 2-ks chunks ----
  f32x4 acc2[2][2];
  #pragma unroll
  for(int m = 0; m < 2; m++) for(int j = 0; j < 2; j++) acc2[m][j] = (f32x4){0,0,0,0};
  #pragma unroll
  for(int kc = 0; kc < 4; kc++){
    bf16x8 cb[2][2];
    #pragma unroll
    for(int j = 0; j < 2; j++)
      #pragma unroll
      for(int k2 = 0; k2 < 2; k2++)
        cb[j][k2] = *(const bf16x8*)(bbHT + j*4096 + (kc*2+k2)*32);
    #pragma unroll
    for(int k2 = 0; k2 < 2; k2++){
      const int ksg = kc*2 + k2;
      bf16x8 af[2];
      #pragma unroll
      for(int m = 0; m < 2; m++){
        int r = m*16 + lrow;
        if(ksg < 4)
          af[m] = *(const bf16x8*)(Alds + r*512 + ((ksg*64 + lk*16) ^ ((r&7)<<4)));
        else
          af[m] = *(const bf16x8*)(RHl + r*256 + (((ksg-4)*64 + lk*16) ^ ((r&7)<<4)));
      }
      #pragma unroll
      for(int j = 0; j < 2; j++)
        #pragma unroll
        for(int m = 0; m < 2; m++)
          acc2[m][j] = __builtin_amdgcn_mfma_f32_16x16x32_bf16(af[m], cb[j][k2], acc2[m][j], 0,0,0);
    }
  }

  // ---- epilogue: out = z*H + (1-z)*tanh(ht);  z from zreg, H from LDS ----
  #pragma unroll
  for(int j = 0; j < 2; j++){
    int col = w*32 + j*16 + lrow;
    float bv = bh[col];
    #pragma unroll
    for(int m = 0; m < 2; m++){
      #pragma unroll
      for(int rr = 0; rr < 4; rr++){
        int row = m*16 + lk*4 + rr;
        int grow = row0 + row;
        if(grow < n){
          float ht = tanh_f(acc2[m][j][rr] + bv);
          float z = zreg[j][m][rr];
          int hb = row*512 + ((2*(128+col)) ^ ((row&7)<<4));
          float Hv = bf2f(*(const short*)(Alds + hb));
          out[(long)grow*DD + col] = z*Hv + (1.f - z)*ht;
        }
      }
    }
  }
}

// ---------------- launch ----------------

extern "C" void kernel_launch(void* const* d_in, const int* in_sizes, int n_in,
                              void* d_out, int out_size, void* d_ws, size_t ws_size,
                              hipStream_t stream){
  const float* x     = (const float*)d_in[0];
  const int*   e32   = (const int*)d_in[1];
  const float* H     = (const float*)d_in[2];
  const float* Wg    = (const float*)d_in[3];
  const float* bg    = (const float*)d_in[4];
  const float* gamma = (const float*)d_in[5];
  const float* beta  = (const float*)d_in[6];
  const float* prelu = (const float*)d_in[7];
  const float* Wz    = (const float*)d_in[8];
  const float* bz    = (const float*)d_in[9];
  const float* Wr    = (const float*)d_in[10];
  const float* br    = (const float*)d_in[11];
  const float* Wh    = (const float*)d_in[12];
  const float* bh    = (const float*)d_in[13];
  float* out = (float*)d_out;
  const int n = in_sizes[0] / DD;
  const int e = in_sizes[1] / 2;
  const int nb = (n + CHUNK - 1) / CHUNK;

  char* ws = (char*)d_ws;
  size_t o = 0;
  auto alloc = [&](size_t bytes)->char*{
    char* p = ws + o; o = (o + bytes + 255) & ~(size_t)255; return p;
  };
  int*   deg    = (int*)  alloc(4L*n);
  float* dinv   = (float*)alloc(4L*n);
  int*   flag   = (int*)  alloc(256);   // flag+sum+sumsq contiguous: one memset
  float* sum    = (float*)alloc(512);
  float* sumsq  = (float*)alloc(512);
  int*   bsum   = (int*)  alloc(4L*nb);
  int*   offs   = (int*)  alloc(4L*n);
  int*   cursor = (int*)  alloc(4L*n);
  int*   srcs   = (int*)  alloc(4L*e);
  short* wtg    = (short*)alloc(128L*128*2);
  short* wtzr   = (short*)alloc(256L*256*2);
  short* wth    = (short*)alloc(128L*256*2);
  short* hraw   = (short*)alloc(2L*n*DD);
  short* xs     = (short*)alloc(2L*n*DD);
  short* Hb     = (short*)alloc(2L*n*DD);

  hipMemsetAsync(flag, 0, 1280, stream);   // flag + sum + sumsq

  int gi = (n + 255)/256;
  int ge = (e + 255)/256;
  int ginit = gi > ge ? gi : ge;
  if(ginit < 448) ginit = 448;             // cover 114688 weight elements
  init_k<<<ginit, 256, 0, stream>>>(deg, e32, flag, Wg, Wz, Wr, Wh, wtg, wtzr, wth, n, e);
  deg_k<<<ge, 256, 0, stream>>>(e32, flag, deg, e, n);
  dscanA_k<<<nb + gi, 256, 0, stream>>>(deg, bsum, dinv, n, nb);
  {
    int cvb = (int)((2L*n*(DD/8) + 255) / 256);
    scanBcvt_k<<<1 + cvb, 256, 0, stream>>>(bsum, nb, x, H, dinv, xs, Hb, n);
  }
  scanC_k<<<nb, 256, 0, stream>>>(deg, bsum, offs, cursor, n);
  fill_k<<<ge, 256, 0, stream>>>(e32, flag, cursor, srcs, e, n);
  gcn_k<<<(n + 63)/64, 256, 0, stream>>>(xs, dinv, offs, deg, srcs, wtg, bg, hraw, sum, sumsq, n);
  gru_k<<<(n + 31)/32, 256, 0, stream>>>(hraw, Hb, wtzr, wth, sum, sumsq, gamma, beta, prelu, bz, br, bh, out, n);
}